// Round 9
// baseline (611.691 us; speedup 1.0000x reference)
//
// CustomTransformerEncoderMoELayerStoich — MI355X (gfx950)
// Round 9: R8 (passing) + depth-2 pipeline on the plain-bf16 GEMM path:
//   triple-buffered LDS ring + counted s_waitcnt vmcnt(4) (never 0 mid-loop).
//   Measured basis: FFN1 MfmaUtil 28.6% == MFMA/(MFMA+exposed-latency) at depth-1.
//   Also: 4 small weight transposes merged into one z-indexed launch.
// Attention core, ASPLIT GEMM loop, routing: unchanged.

#include <hip/hip_runtime.h>
#include <stdint.h>

typedef unsigned short u16;
typedef unsigned int   u32;

using bf16x8 = __attribute__((ext_vector_type(8))) short;
using f32x4  = __attribute__((ext_vector_type(4))) float;

#define N_T   1024
#define N_D   1024
#define N_E   8
#define N_BT  4096
#define LNEPS 1e-5f

// ---------------- helpers ----------------
__device__ __forceinline__ u32 rne2(float a, float b) {
  u32 ua = __float_as_uint(a); ua = (ua + 0x7fffu + ((ua >> 16) & 1u)) >> 16;
  u32 ub = __float_as_uint(b); ub = (ub + 0x7fffu + ((ub >> 16) & 1u)) >> 16;
  return ua | (ub << 16);
}
__device__ __forceinline__ u16 rne1(float a) {
  u32 ua = __float_as_uint(a);
  return (u16)((ua + 0x7fffu + ((ua >> 16) & 1u)) >> 16);
}
__device__ __forceinline__ float bfhi_f(float a) {   // nearest-bf16 value as fp32
  u32 ua = __float_as_uint(a);
  ua = (ua + 0x7fffu + ((ua >> 16) & 1u)) & 0xffff0000u;
  return __uint_as_float(ua);
}
__device__ __forceinline__ int fch(int row) { return (row & 3) ^ ((row >> 2) & 3); }
__device__ __forceinline__ int swz(int row, int chunk) {
  return row * 32 + (((chunk ^ fch(row)) & 3) << 3);
}
__device__ __forceinline__ float wred(float v) {
  #pragma unroll
  for (int o2 = 32; o2 > 0; o2 >>= 1) v += __shfl_xor(v, o2, 64);
  return v;
}
__device__ __forceinline__ f32x4 mfma16(bf16x8 a, bf16x8 b, f32x4 c) {
  return __builtin_amdgcn_mfma_f32_16x16x32_bf16(a, b, c, 0, 0, 0);
}
// async global->LDS, 16B per lane; LDS dest = wave-uniform base + lane*16
typedef __attribute__((address_space(1))) const u32 gas_u32;
typedef __attribute__((address_space(3))) u32 las_u32;
__device__ __forceinline__ void gl16(const void* g, void* l) {
  __builtin_amdgcn_global_load_lds((gas_u32*)g, (las_u32*)l, 16, 0, 0);
}

// ---------------- transpose fp32 [R][C] -> bf16 [C][R] (scale, optional hi/lo split) ---------
template<int SPLIT>
__global__ __launch_bounds__(256)
void transpose_bf16(const float* __restrict__ in, u16* __restrict__ outh,
                    u16* __restrict__ outl, int R, int C, float scale)
{
  __shared__ u16 th[64][68];
  __shared__ u16 tl[SPLIT ? 64 : 1][SPLIT ? 68 : 1];
  const long long zb = (long long)blockIdx.z * R * C;
  const float* srcp = in + zb;
  const int r0 = blockIdx.y * 64, c0 = blockIdx.x * 64;
  const int t = threadIdx.x;
  {
    const int rr = t >> 4, cc = (t & 15) << 2;
    #pragma unroll
    for (int i = 0; i < 4; i++) {
      const int r = rr + i * 16;
      float4 v = *(const float4*)(srcp + (long long)(r0 + r) * C + c0 + cc);
      v.x *= scale; v.y *= scale; v.z *= scale; v.w *= scale;
      if constexpr (SPLIT) {
        float hx = bfhi_f(v.x), hy = bfhi_f(v.y), hz = bfhi_f(v.z), hw = bfhi_f(v.w);
        *(uint2*)&th[r][cc] = make_uint2(rne2(hx, hy), rne2(hz, hw));
        *(uint2*)&tl[r][cc] = make_uint2(rne2(v.x - hx, v.y - hy), rne2(v.z - hz, v.w - hw));
      } else {
        *(uint2*)&th[r][cc] = make_uint2(rne2(v.x, v.y), rne2(v.z, v.w));
      }
    }
  }
  __syncthreads();
  {
    const int c = t >> 2, rs = (t & 3) << 4;
    const long long ob = zb + (long long)(c0 + c) * R + r0 + rs;
    u32 w[8];
    #pragma unroll
    for (int i = 0; i < 8; i++)
      w[i] = (u32)th[rs + 2*i][c] | ((u32)th[rs + 2*i + 1][c] << 16);
    *(uint4*)(outh + ob)     = make_uint4(w[0], w[1], w[2], w[3]);
    *(uint4*)(outh + ob + 8) = make_uint4(w[4], w[5], w[6], w[7]);
    if constexpr (SPLIT) {
      #pragma unroll
      for (int i = 0; i < 8; i++)
        w[i] = (u32)tl[rs + 2*i][c] | ((u32)tl[rs + 2*i + 1][c] << 16);
      *(uint4*)(outl + ob)     = make_uint4(w[0], w[1], w[2], w[3]);
      *(uint4*)(outl + ob + 8) = make_uint4(w[4], w[5], w[6], w[7]);
    }
  }
}

// ---------------- fused Wq/Wk/Wv/Wo transpose (hi/lo split), z selects weight ---------------
__global__ __launch_bounds__(256)
void trans4(const float* __restrict__ Wq, const float* __restrict__ Wk,
            const float* __restrict__ Wv, const float* __restrict__ Wo,
            u16* __restrict__ Bcath, u16* __restrict__ Bcatl,
            u16* __restrict__ WoTh, u16* __restrict__ WoTl)
{
  __shared__ u16 th[64][68];
  __shared__ u16 tl[64][68];
  const int z = blockIdx.z;
  const float* in = (z == 0) ? Wq : (z == 1) ? Wk : (z == 2) ? Wv : Wo;
  u16* outh = (z == 3) ? WoTh : (Bcath + (long long)z * 1024 * 1024);
  u16* outl = (z == 3) ? WoTl : (Bcatl + (long long)z * 1024 * 1024);
  const float scale = (z == 0) ? 0.125f : 1.0f;
  const int r0 = blockIdx.y * 64, c0 = blockIdx.x * 64;
  const int t = threadIdx.x;
  {
    const int rr = t >> 4, cc = (t & 15) << 2;
    #pragma unroll
    for (int i = 0; i < 4; i++) {
      const int r = rr + i * 16;
      float4 v = *(const float4*)(in + (long long)(r0 + r) * 1024 + c0 + cc);
      v.x *= scale; v.y *= scale; v.z *= scale; v.w *= scale;
      float hx = bfhi_f(v.x), hy = bfhi_f(v.y), hz = bfhi_f(v.z), hw = bfhi_f(v.w);
      *(uint2*)&th[r][cc] = make_uint2(rne2(hx, hy), rne2(hz, hw));
      *(uint2*)&tl[r][cc] = make_uint2(rne2(v.x - hx, v.y - hy), rne2(v.z - hz, v.w - hw));
    }
  }
  __syncthreads();
  {
    const int c = t >> 2, rs = (t & 3) << 4;
    const long long ob = (long long)(c0 + c) * 1024 + r0 + rs;
    u32 w[8];
    #pragma unroll
    for (int i = 0; i < 8; i++)
      w[i] = (u32)th[rs + 2*i][c] | ((u32)th[rs + 2*i + 1][c] << 16);
    *(uint4*)(outh + ob)     = make_uint4(w[0], w[1], w[2], w[3]);
    *(uint4*)(outh + ob + 8) = make_uint4(w[4], w[5], w[6], w[7]);
    #pragma unroll
    for (int i = 0; i < 8; i++)
      w[i] = (u32)tl[rs + 2*i][c] | ((u32)tl[rs + 2*i + 1][c] << 16);
    *(uint4*)(outl + ob)     = make_uint4(w[0], w[1], w[2], w[3]);
    *(uint4*)(outl + ob + 8) = make_uint4(w[4], w[5], w[6], w[7]);
  }
}

// ---------------- concat scaled QKV bias: [bq*0.125; bk; bv] ----------------
__global__ __launch_bounds__(256)
void bias_cat(const float* __restrict__ bq, const float* __restrict__ bk,
              const float* __restrict__ bv, float* __restrict__ bcat)
{
  const int i = blockIdx.x * 256 + threadIdx.x;
  if (i < 1024)       bcat[i] = bq[i] * 0.125f;
  else if (i < 2048)  bcat[i] = bk[i - 1024];
  else if (i < 3072)  bcat[i] = bv[i - 2048];
}

// ---------------- V^T per-head transpose: hi/lo bf16 [kv][d] (strided) -> [d][kv] ------------
__global__ __launch_bounds__(256)
void vtrans_bf16(const u16* __restrict__ Vh, const u16* __restrict__ Vl, int ldv,
                 u16* __restrict__ Vth, u16* __restrict__ Vtl)
{
  __shared__ u16 th[64][72];
  __shared__ u16 tl[64][72];
  const int bh = blockIdx.y, b = bh >> 4, h = bh & 15;
  const int kt = blockIdx.x, tid = threadIdx.x;
  {
    const int sr = tid >> 2, scb = (tid & 3) << 4;   // kv row, d col base
    const long long off = (long long)(b * N_T + kt * 64 + sr) * ldv + h * 64 + scb;
    const uint4* vh = (const uint4*)(Vh + off);
    const uint4* vl = (const uint4*)(Vl + off);
    *(uint4*)&th[sr][scb]     = vh[0];
    *(uint4*)&th[sr][scb + 8] = vh[1];
    *(uint4*)&tl[sr][scb]     = vl[0];
    *(uint4*)&tl[sr][scb + 8] = vl[1];
  }
  __syncthreads();
  {
    const int od = tid >> 2, os0 = (tid & 3) << 4;   // d row, kv col base
    u16 wh[16], wl[16];
    #pragma unroll
    for (int i = 0; i < 16; i++) { wh[i] = th[os0 + i][od]; wl[i] = tl[os0 + i][od]; }
    u16* oph = Vth + (long long)(bh * 64 + od) * N_T + kt * 64 + os0;
    u16* opl = Vtl + (long long)(bh * 64 + od) * N_T + kt * 64 + os0;
    *(uint4*)oph = make_uint4((u32)wh[0] | ((u32)wh[1] << 16), (u32)wh[2] | ((u32)wh[3] << 16),
                              (u32)wh[4] | ((u32)wh[5] << 16), (u32)wh[6] | ((u32)wh[7] << 16));
    *(uint4*)(oph + 8) = make_uint4((u32)wh[8] | ((u32)wh[9] << 16), (u32)wh[10] | ((u32)wh[11] << 16),
                                    (u32)wh[12] | ((u32)wh[13] << 16), (u32)wh[14] | ((u32)wh[15] << 16));
    *(uint4*)opl = make_uint4((u32)wl[0] | ((u32)wl[1] << 16), (u32)wl[2] | ((u32)wl[3] << 16),
                              (u32)wl[4] | ((u32)wl[5] << 16), (u32)wl[6] | ((u32)wl[7] << 16));
    *(uint4*)(opl + 8) = make_uint4((u32)wl[8] | ((u32)wl[9] << 16), (u32)wl[10] | ((u32)wl[11] << 16),
                                    (u32)wl[12] | ((u32)wl[13] << 16), (u32)wl[14] | ((u32)wl[15] << 16));
  }
}

// ---------------- 128x128x32 MFMA GEMM (4 waves, 4x4 16x16 frags each) ----------------
// ASPLIT=1: A fp32 -> hi/lo regs -> LDS (3-term), B hi+lo via global_load_lds, single-buffer.
// ASPLIT=0: A,B bf16 via global_load_lds into TRIPLE-BUFFERED LDS ring; counted vmcnt(4)
//           (never 0 mid-loop) -> depth-2 prefetch, ~2 K-steps of latency budget.
// CG-blocked XCD decode: per-XCD chunk = CG columns x all tiles, tile-major within chunk.
// OBF: 0 fp32 out, 1 bf16 out, 2 split hi/lo bf16 out (Cp, Cp2) with cscale folded.
template<int ASPLIT, int GATHER, int DORELU, int DOSCALE, int OBF, int GROUPED, int CG>
__global__ __launch_bounds__(256, 2)
void gemm128(const void* __restrict__ Ap, int lda,
             const u16* __restrict__ Bhp, const u16* __restrict__ Blp,
             long long bstride,
             void* __restrict__ Cp, int ldc,
             const float* __restrict__ biasp, int bias_stride,
             const float* __restrict__ slot_wp,
             const int* __restrict__ tokidx,
             const int2* __restrict__ tilesp, const int* __restrict__ ntilesp,
             int Ksz, void* __restrict__ Cp2, float cscale)
{
  // XCD remap (nwg % 8 == 0 for all grids used) + CG-blocked decode (CG | gridDim.y).
  const int gx = gridDim.x, nwg = gx * gridDim.y;
  const int orig = blockIdx.y * gx + blockIdx.x;
  const int flat = (orig & 7) * (nwg >> 3) + (orig >> 3);
  const int cgsz = gx * CG;
  const int colg = flat / cgsz, rem = flat % cgsz;
  const int bxx = rem / CG;
  const int byy = colg * CG + rem % CG;

  int e = 0, row0;
  if constexpr (GROUPED) {
    if (bxx >= *ntilesp) return;
    const int2 dsc = tilesp[bxx];
    e = dsc.x; row0 = dsc.y;
  } else {
    row0 = bxx * 128;
  }
  const int col0 = byy * 128;

  __shared__ __align__(16) u16 AhS[ASPLIT ? 1 : 3][128 * 32];
  __shared__ __align__(16) u16 BhS[ASPLIT ? 1 : 3][128 * 32];
  __shared__ __align__(16) u16 AlS[ASPLIT ? 128 * 32 : 8];
  __shared__ __align__(16) u16 BlS[ASPLIT ? 128 * 32 : 8];

  const int tid = threadIdx.x, wid = tid >> 6, lane = tid & 63;
  const int wm = (wid >> 1) << 6, wn = (wid & 1) << 6;
  const int l15 = lane & 15, l4 = lane >> 4;

  // async staging geometry: wave w fills rows [w*32, w*32+32); lane -> row, linear chunk
  // lane&3; global chunk = (lane&3)^fch(row) (inverse swizzle; read side uses swz()).
  const int srow0 = wid * 32 + (lane >> 2);
  const int srow1 = srow0 + 16;
  const int sg0 = ((lane & 3) ^ fch(srow0)) << 3;   // u16 elems
  const int sg1 = ((lane & 3) ^ fch(srow1)) << 3;
  const int lo0 = wid * 1024, lo1 = wid * 1024 + 512;

  const u16* Bg0 = Bhp + (long long)e * bstride + (long long)(col0 + srow0) * Ksz + sg0;
  const u16* Bg1 = Bhp + (long long)e * bstride + (long long)(col0 + srow1) * Ksz + sg1;
  const u16* Blg0 = nullptr; const u16* Blg1 = nullptr;
  if constexpr (ASPLIT) {
    Blg0 = Blp + (long long)e * bstride + (long long)(col0 + srow0) * Ksz + sg0;
    Blg1 = Blp + (long long)e * bstride + (long long)(col0 + srow1) * Ksz + sg1;
  }

  const u16* Ag0 = nullptr; const u16* Ag1 = nullptr;
  if constexpr (!ASPLIT) {
    long long ar0, ar1;
    if constexpr (GATHER) { ar0 = tokidx[row0 + srow0]; ar1 = tokidx[row0 + srow1]; }
    else                  { ar0 = row0 + srow0;          ar1 = row0 + srow1; }
    Ag0 = (const u16*)Ap + ar0 * (long long)lda + sg0;
    Ag1 = (const u16*)Ap + ar1 * (long long)lda + sg1;
  }

  f32x4 acc[4][4] = {};
  const int nk = Ksz >> 5;

  if constexpr (!ASPLIT) {
    // ===== triple-buffered plain-bf16 path (depth-2 prefetch, counted vmcnt) =====
    // prologue: stage tiles 0 and 1
    gl16(Ag0, &AhS[0][lo0]); gl16(Ag1, &AhS[0][lo1]);
    gl16(Bg0, &BhS[0][lo0]); gl16(Bg1, &BhS[0][lo1]);
    gl16(Ag0 + 32, &AhS[1][lo0]); gl16(Ag1 + 32, &AhS[1][lo1]);
    gl16(Bg0 + 32, &BhS[1][lo0]); gl16(Bg1 + 32, &BhS[1][lo1]);
    for (int kt = 0; kt < nk; kt++) {
      // wait until this wave's stage(kt) landed (oldest 4 loads); keep stage(kt+1) in flight
      if (kt + 1 < nk) asm volatile("s_waitcnt vmcnt(4)" ::: "memory");
      else             asm volatile("s_waitcnt vmcnt(0)" ::: "memory");
      __syncthreads();                        // all waves' stage(kt) landed
      const int bi = kt % 3;
      bf16x8 ah[4], bh[4];
      #pragma unroll
      for (int i = 0; i < 4; i++) {
        ah[i] = *(const bf16x8*)&AhS[bi][swz(wm + i * 16 + l15, l4)];
        bh[i] = *(const bf16x8*)&BhS[bi][swz(wn + i * 16 + l15, l4)];
      }
      #pragma unroll
      for (int i = 0; i < 4; i++)
        #pragma unroll
        for (int j = 0; j < 4; j++)
          acc[i][j] = mfma16(ah[i], bh[j], acc[i][j]);
      __syncthreads();                        // reads of buf[kt%3] complete
      if (kt + 2 < nk) {
        const int ko = (kt + 2) << 5;
        const int bn = (kt + 2) % 3;
        gl16(Ag0 + ko, &AhS[bn][lo0]);
        gl16(Ag1 + ko, &AhS[bn][lo1]);
        gl16(Bg0 + ko, &BhS[bn][lo0]);
        gl16(Bg1 + ko, &BhS[bn][lo1]);
      }
    }
  } else {
    // ===== fp32-A split path (verified R6 structure) =====
    const int prr = tid >> 1, pc2 = (tid & 1) << 1;
    const float* Arow = (const float*)Ap + (long long)(row0 + prr) * lda;
    uint4 sah0, sah1, sal0, sal1;
    auto gloadA = [&](int k0) {
      const float4* ap = (const float4*)(Arow + k0 + pc2 * 8);
      float4 f0 = ap[0], f1 = ap[1], f2 = ap[2], f3 = ap[3];
      float h0 = bfhi_f(f0.x), h1 = bfhi_f(f0.y), h2 = bfhi_f(f0.z), h3 = bfhi_f(f0.w);
      float h4 = bfhi_f(f1.x), h5 = bfhi_f(f1.y), h6 = bfhi_f(f1.z), h7 = bfhi_f(f1.w);
      sah0 = make_uint4(rne2(h0, h1), rne2(h2, h3), rne2(h4, h5), rne2(h6, h7));
      sal0 = make_uint4(rne2(f0.x - h0, f0.y - h1), rne2(f0.z - h2, f0.w - h3),
                        rne2(f1.x - h4, f1.y - h5), rne2(f1.z - h6, f1.w - h7));
      h0 = bfhi_f(f2.x); h1 = bfhi_f(f2.y); h2 = bfhi_f(f2.z); h3 = bfhi_f(f2.w);
      h4 = bfhi_f(f3.x); h5 = bfhi_f(f3.y); h6 = bfhi_f(f3.z); h7 = bfhi_f(f3.w);
      sah1 = make_uint4(rne2(h0, h1), rne2(h2, h3), rne2(h4, h5), rne2(h6, h7));
      sal1 = make_uint4(rne2(f2.x - h0, f2.y - h1), rne2(f2.z - h2, f2.w - h3),
                        rne2(f3.x - h4, f3.y - h5), rne2(f3.z - h6, f3.w - h7));
    };
    gloadA(0);
    for (int kt = 0; kt < nk; kt++) {
      __syncthreads();
      const int ko = kt << 5;
      *(uint4*)&AhS[0][swz(prr, pc2)]     = sah0;
      *(uint4*)&AhS[0][swz(prr, pc2 + 1)] = sah1;
      *(uint4*)&AlS[swz(prr, pc2)]        = sal0;
      *(uint4*)&AlS[swz(prr, pc2 + 1)]    = sal1;
      gl16(Bg0 + ko, &BhS[0][lo0]);
      gl16(Bg1 + ko, &BhS[0][lo1]);
      gl16(Blg0 + ko, &BlS[lo0]);
      gl16(Blg1 + ko, &BlS[lo1]);
      asm volatile("s_waitcnt vmcnt(0)" ::: "memory");
      __syncthreads();
      if (kt + 1 < nk) gloadA((kt + 1) << 5);

      bf16x8 ah[4], bh[4], al[4], bl[4];
      #pragma unroll
      for (int i = 0; i < 4; i++) {
        const int ar = wm + i * 16 + l15;
        const int br = wn + i * 16 + l15;
        ah[i] = *(const bf16x8*)&AhS[0][swz(ar, l4)];
        bh[i] = *(const bf16x8*)&BhS[0][swz(br, l4)];
        al[i] = *(const bf16x8*)&AlS[swz(ar, l4)];
        bl[i] = *(const bf16x8*)&BlS[swz(br, l4)];
      }
      #pragma unroll
      for (int i = 0; i < 4; i++) {
        #pragma unroll
        for (int j = 0; j < 4; j++) {
          acc[i][j] = mfma16(ah[i], bh[j], acc[i][j]);
          acc[i][j] = mfma16(ah[i], bl[j], acc[i][j]);
          acc[i][j] = mfma16(al[i], bh[j], acc[i][j]);
        }
      }
    }
  }

  #pragma unroll
  for (int i = 0; i < 4; i++) {
    #pragma unroll
    for (int j = 0; j < 4; j++) {
      const int orow0 = row0 + wm + i * 16 + (l4 << 2);
      const int ocol  = col0 + wn + j * 16 + l15;
      const float bv = biasp[(long long)e * bias_stride + col0 + wn + j * 16 + l15];
      #pragma unroll
      for (int q = 0; q < 4; q++) {
        float v = acc[i][j][q] + bv;
        if constexpr (DORELU) v = fmaxf(v, 0.f);
        const long long orow = orow0 + q;
        if constexpr (DOSCALE) v *= slot_wp[orow];
        if constexpr (OBF == 2) {
          const float vs = v * cscale;
          const float hi = bfhi_f(vs);
          ((u16*)Cp )[orow * ldc + ocol] = (u16)(__float_as_uint(hi) >> 16);
          ((u16*)Cp2)[orow * ldc + ocol] = rne1(vs - hi);
        } else if constexpr (OBF == 1) {
          ((u16*)Cp)[orow * ldc + ocol] = rne1(v);
        } else {
          ((float*)Cp)[orow * ldc + ocol] = v;
        }
      }
    }
  }
}

// ---------------- MFMA flash attention with stoichiometric bias ----------------
// grid (B*H=64, T/128=8), block 256 (4 waves); wave handles 32 q rows.
// Q/K pointers are column-offset views into the fused QKV hi/lo buffers (stride ldq).
__global__ __launch_bounds__(256, 2)
void attn_mfma(const u16* __restrict__ Qh, const u16* __restrict__ Ql,
               const u16* __restrict__ Kh, const u16* __restrict__ Kl, int ldq,
               const u16* __restrict__ Vth, const u16* __restrict__ Vtl,
               const float* __restrict__ frac,
               const float* __restrict__ apos, const float* __restrict__ aneg,
               float* __restrict__ ctx)
{
  __shared__ __align__(16) u16 KhS[64 * 64];   // [kv][d], chunk^(kv&7) swizzle
  __shared__ __align__(16) u16 KlS[64 * 64];
  __shared__ __align__(16) u16 VhS[64 * 64];   // [d][kv], same swizzle
  __shared__ __align__(16) u16 VlS[64 * 64];
  __shared__ __align__(16) u16 PS[4][32][72];  // per-wave P[q][kv], +8 pad
  __shared__ __align__(16) float fjS[64];

  const int bh = blockIdx.x, b = bh >> 4, h = bh & 15;
  const int tid = threadIdx.x, wid = tid >> 6, lane = tid & 63;
  const int l15 = lane & 15, l4 = lane >> 4;
  const int q0 = blockIdx.y * 128 + wid * 32;

  // Q fragments (B-operand: n = q = l15, k-chunk = l4), pre-scaled & pre-split
  bf16x8 qh[2][2], ql[2][2];
  #pragma unroll
  for (int ni = 0; ni < 2; ni++) {
    const long long qoff = (long long)(b * N_T + q0 + ni * 16 + l15) * ldq + h * 64 + l4 * 8;
    #pragma unroll
    for (int ks = 0; ks < 2; ks++) {
      qh[ni][ks] = *(const bf16x8*)(Qh + qoff + ks * 32);
      ql[ni][ks] = *(const bf16x8*)(Ql + qoff + ks * 32);
    }
  }
  float fq[2];
  #pragma unroll
  for (int ni = 0; ni < 2; ni++) fq[ni] = frac[b * N_T + q0 + ni * 16 + l15];
  const float ap = apos[h], an = aneg[h];

  f32x4 acc[4][2] = {};                 // O^T: d = md*16+l4*4+reg, q = nq*16+l15
  float mrun[2] = {-3.0e38f, -3.0e38f}, lrun[2] = {0.f, 0.f};

  const int sr = tid >> 2, scb = (tid & 3) << 4;
  const int ch0 = ((scb >> 3) ^ (sr & 7)) << 3;
  const int ch1 = (((scb >> 3) + 1) ^ (sr & 7)) << 3;

  for (int kt = 0; kt < 16; kt++) {
    __syncthreads();
    {
      const long long koff = (long long)(b * N_T + kt * 64 + sr) * ldq + h * 64 + scb;
      const uint4* khp = (const uint4*)(Kh + koff);
      const uint4* klp = (const uint4*)(Kl + koff);
      const long long voff = (long long)(bh * 64 + sr) * N_T + kt * 64 + scb;
      const uint4* vhp = (const uint4*)(Vth + voff);
      const uint4* vlp = (const uint4*)(Vtl + voff);
      *(uint4*)&KhS[sr * 64 + ch0] = khp[0];
      *(uint4*)&KhS[sr * 64 + ch1] = khp[1];
      *(uint4*)&KlS[sr * 64 + ch0] = klp[0];
      *(uint4*)&KlS[sr * 64 + ch1] = klp[1];
      *(uint4*)&VhS[sr * 64 + ch0] = vhp[0];
      *(uint4*)&VhS[sr * 64 + ch1] = vhp[1];
      *(uint4*)&VlS[sr * 64 + ch0] = vlp[0];
      *(uint4*)&VlS[sr * 64 + ch1] = vlp[1];
    }
    if (tid < 64) fjS[tid] = frac[b * N_T + kt * 64 + tid];
    __syncthreads();

    // ---- S^T = K * Q^T (3-term split)
    f32x4 s[4][2] = {};
    #pragma unroll
    for (int ks = 0; ks < 2; ks++) {
      bf16x8 kh[4], kl[4];
      #pragma unroll
      for (int mj = 0; mj < 4; mj++) {
        const int row = mj * 16 + l15;
        const int ch = (((ks << 2) + l4) ^ (row & 7)) << 3;
        kh[mj] = *(const bf16x8*)&KhS[row * 64 + ch];
        kl[mj] = *(const bf16x8*)&KlS[row * 64 + ch];
      }
      #pragma unroll
      for (int mj = 0; mj < 4; mj++) {
        #pragma unroll
        for (int ni = 0; ni < 2; ni++) {
          s[mj][ni] = mfma16(kh[mj], qh[ni][ks], s[mj][ni]);
          s[mj][ni] = mfma16(kh[mj], ql[ni][ks], s[mj][ni]);
          s[mj][ni] = mfma16(kl[mj], qh[ni][ks], s[mj][ni]);
        }
      }
    }

    // ---- bias (scalar fjS reads) ; kv = mj*16 + l4*4 + r, q = ni*16 + l15
    #pragma unroll
    for (int mj = 0; mj < 4; mj++) {
      const int kvb = mj * 16 + l4 * 4;
      const float f0 = fjS[kvb], f1 = fjS[kvb + 1], f2 = fjS[kvb + 2], f3 = fjS[kvb + 3];
      #pragma unroll
      for (int ni = 0; ni < 2; ni++) {
        float d0 = f0 - fq[ni], d1 = f1 - fq[ni], d2 = f2 - fq[ni], d3 = f3 - fq[ni];
        s[mj][ni][0] += (d0 > 0.f ? ap : an) * d0;
        s[mj][ni][1] += (d1 > 0.f ? ap : an) * d1;
        s[mj][ni][2] += (d2 > 0.f ? ap : an) * d2;
        s[mj][ni][3] += (d3 > 0.f ? ap : an) * d3;
      }
    }

    // ---- online softmax
    #pragma unroll
    for (int ni = 0; ni < 2; ni++) {
      float tm = s[0][ni][0];
      #pragma unroll
      for (int mj = 0; mj < 4; mj++) {
        tm = fmaxf(tm, fmaxf(fmaxf(s[mj][ni][0], s[mj][ni][1]),
                             fmaxf(s[mj][ni][2], s[mj][ni][3])));
      }
      tm = fmaxf(tm, __shfl_xor(tm, 16, 64));
      tm = fmaxf(tm, __shfl_xor(tm, 32, 64));
      const float nm = fmaxf(mrun[ni], tm);
      const float cor = __expf(mrun[ni] - nm);
      mrun[ni] = nm;
      lrun[ni] *= cor;
      #pragma unroll
      for (int md = 0; md < 4; md++) {
        acc[md][ni][0] *= cor; acc[md][ni][1] *= cor;
        acc[md][ni][2] *= cor; acc[md][ni][3] *= cor;
      }
      float rsum = 0.f;
      #pragma unroll
      for (int mj = 0; mj < 4; mj++) {
        #pragma unroll
        for (int r = 0; r < 4; r++) {
          const float p = __expf(s[mj][ni][r] - nm);
          s[mj][ni][r] = p;
          rsum += p;
        }
      }
      rsum += __shfl_xor(rsum, 16, 64);
      rsum += __shfl_xor(rsum, 32, 64);
      lrun[ni] += rsum;
    }

    // ---- P hi -> per-wave LDS (C-write-verified mapping), read B-frags
    #pragma unroll
    for (int ni = 0; ni < 2; ni++) {
      #pragma unroll
      for (int mj = 0; mj < 4; mj++) {
        float h0 = bfhi_f(s[mj][ni][0]), h1 = bfhi_f(s[mj][ni][1]);
        float h2 = bfhi_f(s[mj][ni][2]), h3 = bfhi_f(s[mj][ni][3]);
        u32* dst = (u32*)&PS[wid][ni * 16 + l15][mj * 16 + l4 * 4];
        dst[0] = rne2(h0, h1); dst[1] = rne2(h2, h3);
      }
    }
    bf16x8 pbh[2][2];
    #pragma unroll
    for (int ni = 0; ni < 2; ni++)
      #pragma unroll
      for (int ks = 0; ks < 2; ks++)
        pbh[ni][ks] = *(const bf16x8*)&PS[wid][ni * 16 + l15][ks * 32 + l4 * 8];

    // ---- P lo -> same LDS buffer, read B-frags
    #pragma unroll
    for (int ni = 0; ni < 2; ni++) {
      #pragma unroll
      for (int mj = 0; mj < 4; mj++) {
        float p0 = s[mj][ni][0], p1 = s[mj][ni][1], p2 = s[mj][ni][2], p3 = s[mj][ni][3];
        float h0 = bfhi_f(p0), h1 = bfhi_f(p1), h2 = bfhi_f(p2), h3 = bfhi_f(p3);
        u32* dst = (u32*)&PS[wid][ni * 16 + l15][mj * 16 + l4 * 4];
        dst[0] = rne2(p0 - h0, p1 - h1); dst[1] = rne2(p2 - h2, p3 - h3);
      }
    }
    bf16x8 pbl[2][2];
    #pragma unroll
    for (int ni = 0; ni < 2; ni++)
      #pragma unroll
      for (int ks = 0; ks < 2; ks++)
        pbl[ni][ks] = *(const bf16x8*)&PS[wid][ni * 16 + l15][ks * 32 + l4 * 8];

    // ---- O^T += V^T * P^T (3-term split; linear kv pairing)
    #pragma unroll
    for (int md = 0; md < 4; md++) {
      #pragma unroll
      for (int ks = 0; ks < 2; ks++) {
        const int row = md * 16 + l15;
        const int ch = (((ks << 2) + l4) ^ (row & 7)) << 3;
        const bf16x8 vh = *(const bf16x8*)&VhS[row * 64 + ch];
        const bf16x8 vl = *(const bf16x8*)&VlS[row * 64 + ch];
        #pragma unroll
        for (int nq = 0; nq < 2; nq++) {
          acc[md][nq] = mfma16(vh, pbh[nq][ks], acc[md][nq]);
          acc[md][nq] = mfma16(vh, pbl[nq][ks], acc[md][nq]);
          acc[md][nq] = mfma16(vl, pbh[nq][ks], acc[md][nq]);
        }
      }
    }
  }

  // ---- epilogue: ctx[q][d] = O^T[d][q] / l[q]
  const float inv[2] = {1.f / lrun[0], 1.f / lrun[1]};
  #pragma unroll
  for (int nq = 0; nq < 2; nq++) {
    #pragma unroll
    for (int md = 0; md < 4; md++) {
      float4 o;
      o.x = acc[md][nq][0] * inv[nq];
      o.y = acc[md][nq][1] * inv[nq];
      o.z = acc[md][nq][2] * inv[nq];
      o.w = acc[md][nq][3] * inv[nq];
      *(float4*)(ctx + (long long)(b * N_T + q0 + nq * 16 + l15) * N_D +
                 h * 64 + md * 16 + l4 * 4) = o;
    }
  }
}

// ---------------- LN1 + gate softmax + top2 (wave per token; NO device atomics) -------------
__global__ __launch_bounds__(256, 4)
void ln1_gate(const float* __restrict__ src, const float* __restrict__ attnout,
              const float* __restrict__ g, const float* __restrict__ bb,
              const float* __restrict__ gateW, const float* __restrict__ gateb,
              float* __restrict__ xout, u16* __restrict__ xbf,
              int2* __restrict__ tok_top, float2* __restrict__ tok_w)
{
  const int wid = threadIdx.x >> 6, lane = threadIdx.x & 63;
  const int t = blockIdx.x * 4 + wid;
  const float4* s4 = (const float4*)(src + (long long)t * N_D);
  const float4* a4 = (const float4*)(attnout + (long long)t * N_D);
  float4 v[4];
  float sum = 0.f;
  #pragma unroll
  for (int c = 0; c < 4; c++) {
    const int idx = c * 64 + lane;
    float4 a = s4[idx], b2 = a4[idx];
    v[c] = make_float4(a.x + b2.x, a.y + b2.y, a.z + b2.z, a.w + b2.w);
    sum += v[c].x + v[c].y + v[c].z + v[c].w;
  }
  sum = wred(sum);
  const float mu = sum * (1.f / 1024.f);
  float s2 = 0.f;
  #pragma unroll
  for (int c = 0; c < 4; c++) {
    float dx = v[c].x - mu, dy = v[c].y - mu, dz = v[c].z - mu, dw = v[c].w - mu;
    s2 += dx * dx + dy * dy + dz * dz + dw * dw;
  }
  s2 = wred(s2);
  const float rs = rsqrtf(s2 * (1.f / 1024.f) + LNEPS);
  float acc[8];
  #pragma unroll
  for (int e2 = 0; e2 < 8; e2++) acc[e2] = 0.f;
  #pragma unroll
  for (int c = 0; c < 4; c++) {
    const int idx = c * 64 + lane;
    float4 gv = ((const float4*)g)[idx], bv = ((const float4*)bb)[idx];
    float xa[4];
    xa[0] = (v[c].x - mu) * rs * gv.x + bv.x;
    xa[1] = (v[c].y - mu) * rs * gv.y + bv.y;
    xa[2] = (v[c].z - mu) * rs * gv.z + bv.z;
    xa[3] = (v[c].w - mu) * rs * gv.w + bv.w;
    ((float4*)(xout + (long long)t * N_D))[idx] = make_float4(xa[0], xa[1], xa[2], xa[3]);
    *(uint2*)&xbf[(long long)t * N_D + idx * 4] =
        make_uint2(rne2(xa[0], xa[1]), rne2(xa[2], xa[3]));
    #pragma unroll
    for (int ii = 0; ii < 4; ii++) {
      const float xs = xa[ii];
      const float4* gw = (const float4*)(gateW + ((long long)(idx * 4 + ii)) * N_E);
      float4 w0 = gw[0], w1 = gw[1];
      acc[0] += xs * w0.x; acc[1] += xs * w0.y; acc[2] += xs * w0.z; acc[3] += xs * w0.w;
      acc[4] += xs * w1.x; acc[5] += xs * w1.y; acc[6] += xs * w1.z; acc[7] += xs * w1.w;
    }
  }
  #pragma unroll
  for (int e2 = 0; e2 < 8; e2++) acc[e2] = wred(acc[e2]);
  if (lane == 0) {
    float lg[8];
    #pragma unroll
    for (int e2 = 0; e2 < 8; e2++) lg[e2] = acc[e2] + gateb[e2];
    float mx = lg[0];
    #pragma unroll
    for (int e2 = 1; e2 < 8; e2++) mx = fmaxf(mx, lg[e2]);
    float Z = 0.f;
    #pragma unroll
    for (int e2 = 0; e2 < 8; e2++) Z += __expf(lg[e2] - mx);
    int e0 = 0; float v0 = lg[0];
    #pragma unroll
    for (int e2 = 1; e2 < 8; e2++) if (lg[e2] > v0) { v0 = lg[e2]; e0 = e2; }
    int e1 = -1; float v1 = -3.4e38f;
    #pragma unroll
    for (int e2 = 0; e2 < 8; e2++) if (e2 != e0 && lg[e2] > v1) { v1 = lg[e2]; e1 = e2; }
    tok_top[t] = make_int2(e0, e1);
    tok_w[t] = make_float2(__expf(v0 - mx) / Z, __expf(v1 - mx) / Z);
  }
}

// ---------------- routing: histogram tok_top, offsets, tiles, padding fill ----------------
__global__ __launch_bounds__(256)
void route_build(const int2* __restrict__ tok_top, int* __restrict__ offsets,
                 int* __restrict__ cursors, int* __restrict__ ntiles,
                 int2* __restrict__ tiles, int* __restrict__ token_idx,
                 float* __restrict__ slot_w)
{
  __shared__ int cnt[N_E];
  __shared__ int soff[N_E + 1];
  __shared__ int scnt[N_E];
  const int tid = threadIdx.x;
  if (tid < N_E) cnt[tid] = 0;
  __syncthreads();
  int lc0 = 0, lc1 = 0, lc2 = 0, lc3 = 0, lc4 = 0, lc5 = 0, lc6 = 0, lc7 = 0;
  for (int t = tid; t < N_BT; t += 256) {
    const int2 ee = tok_top[t];
    lc0 += (ee.x == 0) + (ee.y == 0); lc1 += (ee.x == 1) + (ee.y == 1);
    lc2 += (ee.x == 2) + (ee.y == 2); lc3 += (ee.x == 3) + (ee.y == 3);
    lc4 += (ee.x == 4) + (ee.y == 4); lc5 += (ee.x == 5) + (ee.y == 5);
    lc6 += (ee.x == 6) + (ee.y == 6); lc7 += (ee.x == 7) + (ee.y == 7);
  }
  if (lc0) atomicAdd(&cnt[0], lc0); if (lc1) atomicAdd(&cnt[1], lc1);
  if (lc2) atomicAdd(&cnt[2], lc2); if (lc3) atomicAdd(&cnt[3], lc3);
  if (lc4) atomicAdd(&cnt[4], lc4); if (lc5) atomicAdd(&cnt[5], lc5);
  if (lc6) atomicAdd(&cnt[6], lc6); if (lc7) atomicAdd(&cnt[7], lc7);
  __syncthreads();
  if (tid == 0) {
    int off = 0, nt = 0;
    for (int ex = 0; ex < N_E; ex++) {
      soff[ex] = off; offsets[ex] = off; cursors[ex] = 0;
      const int c = cnt[ex];
      scnt[ex] = c;
      const int pt = (c + 127) >> 7;
      for (int i = 0; i < pt; i++) { tiles[nt] = make_int2(ex, off + i * 128); nt++; }
      off += pt << 7;
    }
    soff[N_E] = off; offsets[N_E] = off;
    *ntiles = nt;
  }
  __syncthreads();
  for (int ex = 0; ex < N_E; ex++)
    for (int s = soff[ex] + scnt[ex] + tid; s < soff[ex + 1]; s += 256) {
      token_idx[s] = 0; slot_w[s] = 0.f;
    }
}

__global__ __launch_bounds__(256)
void route_scatter(const int2* __restrict__ tok_top, const float2* __restrict__ tok_w,
                   const int* __restrict__ offsets, int* __restrict__ cursors,
                   int* __restrict__ token_idx, float* __restrict__ slot_w,
                   int* __restrict__ slotA, int* __restrict__ slotB)
{
  const int t = blockIdx.x * 256 + threadIdx.x;
  if (t >= N_BT) return;
  const int2 ee = tok_top[t];
  const float2 ww = tok_w[t];
  int p = atomicAdd(&cursors[ee.x], 1);
  int s = offsets[ee.x] + p;
  token_idx[s] = t; slot_w[s] = ww.x; slotA[t] = s;
  p = atomicAdd(&cursors[ee.y], 1);
  s = offsets[ee.y] + p;
  token_idx[s] = t; slot_w[s] = ww.y; slotB[t] = s;
}

// ---------------- final: y = LN2(x + out2[sA] + out2[sB]) ----------------
__global__ __launch_bounds__(256, 4)
void final_ln2(const float* __restrict__ x, const float* __restrict__ out2,
               const int* __restrict__ slotA, const int* __restrict__ slotB,
               const float* __restrict__ g, const float* __restrict__ bb,
               float* __restrict__ out)
{
  const int wid = threadIdx.x >> 6, lane = threadIdx.x & 63;
  const int t = blockIdx.x * 4 + wid;
  const int sA = slotA[t], sB = slotB[t];
  const float4* xr = (const float4*)(x + (long long)t * N_D);
  const float4* pa = (const float4*)(out2 + (long long)sA * N_D);
  const float4* pb = (const float4*)(out2 + (long long)sB * N_D);
  float4 v[4];
  float sum = 0.f;
  #pragma unroll
  for (int c = 0; c < 4; c++) {
    const int idx = c * 64 + lane;
    float4 a = xr[idx], b2 = pa[idx], c2 = pb[idx];
    v[c] = make_float4(a.x + b2.x + c2.x, a.y + b2.y + c2.y,
                       a.z + b2.z + c2.z, a.w + b2.w + c2.w);
    sum += v[c].x + v[c].y + v[c].z + v[c].w;
  }
  sum = wred(sum);
  const float mu = sum * (1.f / 1024.f);
  float s2 = 0.f;
  #pragma unroll
  for (int c = 0; c < 4; c++) {
    float dx = v[c].x - mu, dy = v[c].y - mu, dz = v[c].z - mu, dw = v[c].w - mu;
    s2 += dx * dx + dy * dy + dz * dz + dw * dw;
  }
  s2 = wred(s2);
  const float rs = rsqrtf(s2 * (1.f / 1024.f) + LNEPS);
  #pragma unroll
  for (int c = 0; c < 4; c++) {
    const int idx = c * 64 + lane;
    float4 gv = ((const float4*)g)[idx], bv = ((const float4*)bb)[idx];
    float4 o;
    o.x = (v[c].x - mu) * rs * gv.x + bv.x;
    o.y = (v[c].y - mu) * rs * gv.y + bv.y;
    o.z = (v[c].z - mu) * rs * gv.z + bv.z;
    o.w = (v[c].w - mu) * rs * gv.w + bv.w;
    ((float4*)(out + (long long)t * N_D))[idx] = o;
  }
}

// ---------------- launch ----------------
extern "C" void kernel_launch(void* const* d_in, const int* in_sizes, int n_in,
                              void* d_out, int out_size, void* d_ws, size_t ws_size,
                              hipStream_t stream)
{
  const float* src   = (const float*)d_in[0];
  const float* frac  = (const float*)d_in[1];
  const float* Wq    = (const float*)d_in[2];
  const float* bq    = (const float*)d_in[3];
  const float* Wk    = (const float*)d_in[4];
  const float* bk    = (const float*)d_in[5];
  const float* Wv    = (const float*)d_in[6];
  const float* bv    = (const float*)d_in[7];
  const float* Wo    = (const float*)d_in[8];
  const float* bo    = (const float*)d_in[9];
  const float* apos  = (const float*)d_in[10];
  const float* aneg  = (const float*)d_in[11];
  const float* gateW = (const float*)d_in[12];
  const float* gateb = (const float*)d_in[13];
  const float* W1    = (const float*)d_in[14];
  const float* b1    = (const float*)d_in[15];
  const float* W2    = (const float*)d_in[16];
  const float* b2    = (const float*)d_in[17];
  const float* ln1g  = (const float*)d_in[18];
  const float* ln1b  = (const float*)d_in[19];
  const float* ln2g  = (const float*)d_in[20];
  const float* ln2b  = (const float*)d_in[21];
  float* out = (float*)d_out;

  char* ws = (char*)d_ws;
  const size_t MB = 1ull << 20;
  u16* Bcath = (u16*)(ws + 0 * MB);
  u16* Bcatl = (u16*)(ws + 6 * MB);
  u16* WoTh  = (u16*)(ws + 12 * MB);
  u16* WoTl  = (u16*)(ws + 14 * MB);
  u16*   W1T  = (u16*)(ws + 16 * MB);    // 64 MB, dead after FFN GEMM1
  float* out2 = (float*)(ws + 16 * MB);  // <=38 MB, alias (written after W1T dead)
  u16*   W2T  = (u16*)(ws + 80 * MB);    // 64 MB
  u16*   QKVh = (u16*)(ws + 144 * MB);   // 24 MB: [4096][3072] hi (Q|K|V)
  u16*   QKVl = (u16*)(ws + 168 * MB);   // 24 MB lo
  u16*   Vth  = (u16*)(ws + 192 * MB);   // 8 MB per-head V^T hi
  u16*   Vtl  = (u16*)(ws + 200 * MB);   // 8 MB per-head V^T lo
  float* ctxb = (float*)(ws + 208 * MB); // 16 MB
  float* attnb= (float*)(ws + 144 * MB); // 16 MB alias (QKVh dead after attn)
  u16*   hb   = (u16*)(ws + 144 * MB);   // <=72 MB alias (all of 144-216 dead by FFN1)
  float* xb   = (float*)(ws + 224 * MB); // 16 MB fp32 -> total 240 MB
  u16*   xbf  = (u16*)(ws + 4 * MB);     // 8 MB bf16 alias (Bcat dead by ln1_gate)
  float* bcat = (float*)(ws + 240 * MB); // 12 KB
  char* misc = ws + 0;                   // aliases Bcat region (dead by routing phase)
  int*    cursors   = (int*)(misc + 64);
  int*    offsets   = (int*)(misc + 128);
  int*    ntiles    = (int*)(misc + 256);
  int2*   tiles     = (int2*)(misc + 512);
  int2*   tok_top   = (int2*)(misc + 2048);
  float2* tok_w     = (float2*)(misc + 2048 + 32768);
  int*    token_idx = (int*)(misc + 2048 + 65536);
  float*  slot_w    = (float*)(misc + 2048 + 65536 + 36864);
  int*    slotA     = (int*)(misc + 2048 + 65536 + 73728);
  int*    slotB     = (int*)(misc + 2048 + 65536 + 73728 + 16384);

  dim3 b256(256);
  // fused small-weight transposes: z = {Wq*0.125, Wk, Wv, Wo}
  trans4<<<dim3(16, 16, 4), b256, 0, stream>>>(Wq, Wk, Wv, Wo, Bcath, Bcatl, WoTh, WoTl);
  transpose_bf16<0><<<dim3(64, 16, 8), b256, 0, stream>>>(W1, W1T, nullptr, 1024, 4096, 1.0f);
  transpose_bf16<0><<<dim3(16, 64, 8), b256, 0, stream>>>(W2, W2T, nullptr, 4096, 1024, 1.0f);
  bias_cat<<<dim3(12), b256, 0, stream>>>(bq, bk, bv, bcat);

  // fused QKV projection: [4096][3072] hi/lo bf16 (Q cols pre-scaled via Wq/bq); CG=3
  gemm128<1, 0, 0, 0, 2, 0, 3><<<dim3(32, 24), b256, 0, stream>>>(
      src, 1024, Bcath, Bcatl, 0, QKVh, 3072, bcat, 0, nullptr, nullptr, nullptr, nullptr,
      1024, QKVl, 1.0f);

  vtrans_bf16<<<dim3(16, 64), b256, 0, stream>>>(QKVh + 2048, QKVl + 2048, 3072, Vth, Vtl);

  attn_mfma<<<dim3(64, 8), b256, 0, stream>>>(QKVh, QKVl, QKVh + 1024, QKVl + 1024, 3072,
                                              Vth, Vtl, frac, apos, aneg, ctxb);

  gemm128<1, 0, 0, 0, 0, 0, 1><<<dim3(32, 8), b256, 0, stream>>>(
      ctxb, 1024, WoTh, WoTl, 0, attnb, 1024, bo, 0, nullptr, nullptr, nullptr, nullptr,
      1024, nullptr, 1.0f);

  ln1_gate<<<dim3(1024), b256, 0, stream>>>(src, attnb, ln1g, ln1b, gateW, gateb,
                                            xb, xbf, tok_top, tok_w);
  route_build<<<dim3(1), b256, 0, stream>>>(tok_top, offsets, cursors, ntiles,
                                            tiles, token_idx, slot_w);
  route_scatter<<<dim3(16), b256, 0, stream>>>(tok_top, tok_w, offsets, cursors,
                                               token_idx, slot_w, slotA, slotB);

  // grouped MoE FFN (bf16 A+B, triple-buffered global_load_lds pipeline)
  gemm128<0, 1, 1, 0, 1, 1, 4><<<dim3(72, 32), b256, 0, stream>>>(
      xbf, 1024, W1T, nullptr, 4096ll * 1024, hb, 4096, b1, 4096,
      nullptr, token_idx, tiles, ntiles, 1024, nullptr, 1.0f);
  gemm128<0, 0, 0, 1, 0, 1, 8><<<dim3(72, 8), b256, 0, stream>>>(
      hb, 4096, W2T, nullptr, 1024ll * 4096, out2, 1024, b2, 1024,
      slot_w, nullptr, tiles, ntiles, 4096, nullptr, 1.0f);

  final_ln2<<<dim3(1024), b256, 0, stream>>>(xb, out2, slotA, slotB, ln2g, ln2b, out);
}

// Round 10
// 581.170 us; speedup vs baseline: 1.0525x; 1.0525x over previous
//
// CustomTransformerEncoderMoELayerStoich — MI355X (gfx950)
// Round 10: post-mortem of R9's occupancy cliff (48KB LDS -> 2 blocks/CU, MfmaUtil fell).
//   1) plain-bf16 GEMM path reverted to R8's proven 32KB double-buffer
//   2) ASPLIT path: B staged via register prefetch (R5 structure) — loads for kt+1 issue
//      before MFMA(kt), hidden under ~750cy of MFMA; no exposed-latency gl16 window
//   3) FFN2 output bf16 (halves WRITE + LN2 gather read); final_ln2 decodes
// Attention core, routing, transposes unchanged.

#include <hip/hip_runtime.h>
#include <stdint.h>

typedef unsigned short u16;
typedef unsigned int   u32;

using bf16x8 = __attribute__((ext_vector_type(8))) short;
using f32x4  = __attribute__((ext_vector_type(4))) float;

#define N_T   1024
#define N_D   1024
#define N_E   8
#define N_BT  4096
#define LNEPS 1e-5f

// ---------------- helpers ----------------
__device__ __forceinline__ u32 rne2(float a, float b) {
  u32 ua = __float_as_uint(a); ua = (ua + 0x7fffu + ((ua >> 16) & 1u)) >> 16;
  u32 ub = __float_as_uint(b); ub = (ub + 0x7fffu + ((ub >> 16) & 1u)) >> 16;
  return ua | (ub << 16);
}
__device__ __forceinline__ u16 rne1(float a) {
  u32 ua = __float_as_uint(a);
  return (u16)((ua + 0x7fffu + ((ua >> 16) & 1u)) >> 16);
}
__device__ __forceinline__ float bfhi_f(float a) {   // nearest-bf16 value as fp32
  u32 ua = __float_as_uint(a);
  ua = (ua + 0x7fffu + ((ua >> 16) & 1u)) & 0xffff0000u;
  return __uint_as_float(ua);
}
__device__ __forceinline__ int fch(int row) { return (row & 3) ^ ((row >> 2) & 3); }
__device__ __forceinline__ int swz(int row, int chunk) {
  return row * 32 + (((chunk ^ fch(row)) & 3) << 3);
}
__device__ __forceinline__ float wred(float v) {
  #pragma unroll
  for (int o2 = 32; o2 > 0; o2 >>= 1) v += __shfl_xor(v, o2, 64);
  return v;
}
__device__ __forceinline__ f32x4 mfma16(bf16x8 a, bf16x8 b, f32x4 c) {
  return __builtin_amdgcn_mfma_f32_16x16x32_bf16(a, b, c, 0, 0, 0);
}
// async global->LDS, 16B per lane; LDS dest = wave-uniform base + lane*16
typedef __attribute__((address_space(1))) const u32 gas_u32;
typedef __attribute__((address_space(3))) u32 las_u32;
__device__ __forceinline__ void gl16(const void* g, void* l) {
  __builtin_amdgcn_global_load_lds((gas_u32*)g, (las_u32*)l, 16, 0, 0);
}

// ---------------- transpose fp32 [R][C] -> bf16 [C][R] ----------------
template<int SPLIT>
__global__ __launch_bounds__(256)
void transpose_bf16(const float* __restrict__ in, u16* __restrict__ outh,
                    u16* __restrict__ outl, int R, int C, float scale)
{
  __shared__ u16 th[64][68];
  __shared__ u16 tl[SPLIT ? 64 : 1][SPLIT ? 68 : 1];
  const long long zb = (long long)blockIdx.z * R * C;
  const float* srcp = in + zb;
  const int r0 = blockIdx.y * 64, c0 = blockIdx.x * 64;
  const int t = threadIdx.x;
  {
    const int rr = t >> 4, cc = (t & 15) << 2;
    #pragma unroll
    for (int i = 0; i < 4; i++) {
      const int r = rr + i * 16;
      float4 v = *(const float4*)(srcp + (long long)(r0 + r) * C + c0 + cc);
      v.x *= scale; v.y *= scale; v.z *= scale; v.w *= scale;
      if constexpr (SPLIT) {
        float hx = bfhi_f(v.x), hy = bfhi_f(v.y), hz = bfhi_f(v.z), hw = bfhi_f(v.w);
        *(uint2*)&th[r][cc] = make_uint2(rne2(hx, hy), rne2(hz, hw));
        *(uint2*)&tl[r][cc] = make_uint2(rne2(v.x - hx, v.y - hy), rne2(v.z - hz, v.w - hw));
      } else {
        *(uint2*)&th[r][cc] = make_uint2(rne2(v.x, v.y), rne2(v.z, v.w));
      }
    }
  }
  __syncthreads();
  {
    const int c = t >> 2, rs = (t & 3) << 4;
    const long long ob = zb + (long long)(c0 + c) * R + r0 + rs;
    u32 w[8];
    #pragma unroll
    for (int i = 0; i < 8; i++)
      w[i] = (u32)th[rs + 2*i][c] | ((u32)th[rs + 2*i + 1][c] << 16);
    *(uint4*)(outh + ob)     = make_uint4(w[0], w[1], w[2], w[3]);
    *(uint4*)(outh + ob + 8) = make_uint4(w[4], w[5], w[6], w[7]);
    if constexpr (SPLIT) {
      #pragma unroll
      for (int i = 0; i < 8; i++)
        w[i] = (u32)tl[rs + 2*i][c] | ((u32)tl[rs + 2*i + 1][c] << 16);
      *(uint4*)(outl + ob)     = make_uint4(w[0], w[1], w[2], w[3]);
      *(uint4*)(outl + ob + 8) = make_uint4(w[4], w[5], w[6], w[7]);
    }
  }
}

// ---------------- fused Wq/Wk/Wv/Wo transpose (hi/lo split), z selects weight ---------------
__global__ __launch_bounds__(256)
void trans4(const float* __restrict__ Wq, const float* __restrict__ Wk,
            const float* __restrict__ Wv, const float* __restrict__ Wo,
            u16* __restrict__ Bcath, u16* __restrict__ Bcatl,
            u16* __restrict__ WoTh, u16* __restrict__ WoTl)
{
  __shared__ u16 th[64][68];
  __shared__ u16 tl[64][68];
  const int z = blockIdx.z;
  const float* in = (z == 0) ? Wq : (z == 1) ? Wk : (z == 2) ? Wv : Wo;
  u16* outh = (z == 3) ? WoTh : (Bcath + (long long)z * 1024 * 1024);
  u16* outl = (z == 3) ? WoTl : (Bcatl + (long long)z * 1024 * 1024);
  const float scale = (z == 0) ? 0.125f : 1.0f;
  const int r0 = blockIdx.y * 64, c0 = blockIdx.x * 64;
  const int t = threadIdx.x;
  {
    const int rr = t >> 4, cc = (t & 15) << 2;
    #pragma unroll
    for (int i = 0; i < 4; i++) {
      const int r = rr + i * 16;
      float4 v = *(const float4*)(in + (long long)(r0 + r) * 1024 + c0 + cc);
      v.x *= scale; v.y *= scale; v.z *= scale; v.w *= scale;
      float hx = bfhi_f(v.x), hy = bfhi_f(v.y), hz = bfhi_f(v.z), hw = bfhi_f(v.w);
      *(uint2*)&th[r][cc] = make_uint2(rne2(hx, hy), rne2(hz, hw));
      *(uint2*)&tl[r][cc] = make_uint2(rne2(v.x - hx, v.y - hy), rne2(v.z - hz, v.w - hw));
    }
  }
  __syncthreads();
  {
    const int c = t >> 2, rs = (t & 3) << 4;
    const long long ob = (long long)(c0 + c) * 1024 + r0 + rs;
    u32 w[8];
    #pragma unroll
    for (int i = 0; i < 8; i++)
      w[i] = (u32)th[rs + 2*i][c] | ((u32)th[rs + 2*i + 1][c] << 16);
    *(uint4*)(outh + ob)     = make_uint4(w[0], w[1], w[2], w[3]);
    *(uint4*)(outh + ob + 8) = make_uint4(w[4], w[5], w[6], w[7]);
    #pragma unroll
    for (int i = 0; i < 8; i++)
      w[i] = (u32)tl[rs + 2*i][c] | ((u32)tl[rs + 2*i + 1][c] << 16);
    *(uint4*)(outl + ob)     = make_uint4(w[0], w[1], w[2], w[3]);
    *(uint4*)(outl + ob + 8) = make_uint4(w[4], w[5], w[6], w[7]);
  }
}

// ---------------- concat scaled QKV bias: [bq*0.125; bk; bv] ----------------
__global__ __launch_bounds__(256)
void bias_cat(const float* __restrict__ bq, const float* __restrict__ bk,
              const float* __restrict__ bv, float* __restrict__ bcat)
{
  const int i = blockIdx.x * 256 + threadIdx.x;
  if (i < 1024)       bcat[i] = bq[i] * 0.125f;
  else if (i < 2048)  bcat[i] = bk[i - 1024];
  else if (i < 3072)  bcat[i] = bv[i - 2048];
}

// ---------------- V^T per-head transpose: hi/lo bf16 [kv][d] (strided) -> [d][kv] ------------
__global__ __launch_bounds__(256)
void vtrans_bf16(const u16* __restrict__ Vh, const u16* __restrict__ Vl, int ldv,
                 u16* __restrict__ Vth, u16* __restrict__ Vtl)
{
  __shared__ u16 th[64][72];
  __shared__ u16 tl[64][72];
  const int bh = blockIdx.y, b = bh >> 4, h = bh & 15;
  const int kt = blockIdx.x, tid = threadIdx.x;
  {
    const int sr = tid >> 2, scb = (tid & 3) << 4;   // kv row, d col base
    const long long off = (long long)(b * N_T + kt * 64 + sr) * ldv + h * 64 + scb;
    const uint4* vh = (const uint4*)(Vh + off);
    const uint4* vl = (const uint4*)(Vl + off);
    *(uint4*)&th[sr][scb]     = vh[0];
    *(uint4*)&th[sr][scb + 8] = vh[1];
    *(uint4*)&tl[sr][scb]     = vl[0];
    *(uint4*)&tl[sr][scb + 8] = vl[1];
  }
  __syncthreads();
  {
    const int od = tid >> 2, os0 = (tid & 3) << 4;   // d row, kv col base
    u16 wh[16], wl[16];
    #pragma unroll
    for (int i = 0; i < 16; i++) { wh[i] = th[os0 + i][od]; wl[i] = tl[os0 + i][od]; }
    u16* oph = Vth + (long long)(bh * 64 + od) * N_T + kt * 64 + os0;
    u16* opl = Vtl + (long long)(bh * 64 + od) * N_T + kt * 64 + os0;
    *(uint4*)oph = make_uint4((u32)wh[0] | ((u32)wh[1] << 16), (u32)wh[2] | ((u32)wh[3] << 16),
                              (u32)wh[4] | ((u32)wh[5] << 16), (u32)wh[6] | ((u32)wh[7] << 16));
    *(uint4*)(oph + 8) = make_uint4((u32)wh[8] | ((u32)wh[9] << 16), (u32)wh[10] | ((u32)wh[11] << 16),
                                    (u32)wh[12] | ((u32)wh[13] << 16), (u32)wh[14] | ((u32)wh[15] << 16));
    *(uint4*)opl = make_uint4((u32)wl[0] | ((u32)wl[1] << 16), (u32)wl[2] | ((u32)wl[3] << 16),
                              (u32)wl[4] | ((u32)wl[5] << 16), (u32)wl[6] | ((u32)wl[7] << 16));
    *(uint4*)(opl + 8) = make_uint4((u32)wl[8] | ((u32)wl[9] << 16), (u32)wl[10] | ((u32)wl[11] << 16),
                                    (u32)wl[12] | ((u32)wl[13] << 16), (u32)wl[14] | ((u32)wl[15] << 16));
  }
}

// ---------------- 128x128x32 MFMA GEMM (4 waves, 4x4 16x16 frags each) ----------------
// ASPLIT=1: A fp32 + B hi/lo ALL register-prefetched (loads for kt+1 issued before MFMA(kt),
//           hidden under ~750cy MFMA), regs -> swizzled LDS writes. 32KB LDS.
// ASPLIT=0: A,B bf16 via global_load_lds, R8-proven 32KB double buffer (3 blocks/CU).
// CG-blocked XCD decode: per-XCD chunk = CG columns x all tiles, tile-major within chunk.
// OBF: 0 fp32 out, 1 bf16 out, 2 split hi/lo bf16 out (Cp, Cp2) with cscale folded.
template<int ASPLIT, int GATHER, int DORELU, int DOSCALE, int OBF, int GROUPED, int CG>
__global__ __launch_bounds__(256, 2)
void gemm128(const void* __restrict__ Ap, int lda,
             const u16* __restrict__ Bhp, const u16* __restrict__ Blp,
             long long bstride,
             void* __restrict__ Cp, int ldc,
             const float* __restrict__ biasp, int bias_stride,
             const float* __restrict__ slot_wp,
             const int* __restrict__ tokidx,
             const int2* __restrict__ tilesp, const int* __restrict__ ntilesp,
             int Ksz, void* __restrict__ Cp2, float cscale)
{
  // XCD remap (nwg % 8 == 0 for all grids used) + CG-blocked decode (CG | gridDim.y).
  const int gx = gridDim.x, nwg = gx * gridDim.y;
  const int orig = blockIdx.y * gx + blockIdx.x;
  const int flat = (orig & 7) * (nwg >> 3) + (orig >> 3);
  const int cgsz = gx * CG;
  const int colg = flat / cgsz, rem = flat % cgsz;
  const int bxx = rem / CG;
  const int byy = colg * CG + rem % CG;

  int e = 0, row0;
  if constexpr (GROUPED) {
    if (bxx >= *ntilesp) return;
    const int2 dsc = tilesp[bxx];
    e = dsc.x; row0 = dsc.y;
  } else {
    row0 = bxx * 128;
  }
  const int col0 = byy * 128;

  __shared__ __align__(16) u16 AhS[ASPLIT ? 1 : 2][128 * 32];
  __shared__ __align__(16) u16 BhS[ASPLIT ? 1 : 2][128 * 32];
  __shared__ __align__(16) u16 AlS[ASPLIT ? 128 * 32 : 8];
  __shared__ __align__(16) u16 BlS[ASPLIT ? 128 * 32 : 8];

  const int tid = threadIdx.x, wid = tid >> 6, lane = tid & 63;
  const int wm = (wid >> 1) << 6, wn = (wid & 1) << 6;
  const int l15 = lane & 15, l4 = lane >> 4;

  f32x4 acc[4][4] = {};
  const int nk = Ksz >> 5;

  if constexpr (!ASPLIT) {
    // ===== R8-proven double-buffered plain-bf16 path (gl16, 32KB) =====
    const int srow0 = wid * 32 + (lane >> 2);
    const int srow1 = srow0 + 16;
    const int sg0 = ((lane & 3) ^ fch(srow0)) << 3;   // u16 elems
    const int sg1 = ((lane & 3) ^ fch(srow1)) << 3;
    const int lo0 = wid * 1024, lo1 = wid * 1024 + 512;

    const u16* Bg0 = Bhp + (long long)e * bstride + (long long)(col0 + srow0) * Ksz + sg0;
    const u16* Bg1 = Bhp + (long long)e * bstride + (long long)(col0 + srow1) * Ksz + sg1;
    long long ar0, ar1;
    if constexpr (GATHER) { ar0 = tokidx[row0 + srow0]; ar1 = tokidx[row0 + srow1]; }
    else                  { ar0 = row0 + srow0;          ar1 = row0 + srow1; }
    const u16* Ag0 = (const u16*)Ap + ar0 * (long long)lda + sg0;
    const u16* Ag1 = (const u16*)Ap + ar1 * (long long)lda + sg1;

    gl16(Ag0, &AhS[0][lo0]); gl16(Ag1, &AhS[0][lo1]);
    gl16(Bg0, &BhS[0][lo0]); gl16(Bg1, &BhS[0][lo1]);
    asm volatile("s_waitcnt vmcnt(0)" ::: "memory");
    __syncthreads();
    int cur = 0;
    for (int kt = 0; kt < nk; kt++) {
      if (kt + 1 < nk) {
        const int ko = (kt + 1) << 5;
        gl16(Ag0 + ko, &AhS[cur ^ 1][lo0]);
        gl16(Ag1 + ko, &AhS[cur ^ 1][lo1]);
        gl16(Bg0 + ko, &BhS[cur ^ 1][lo0]);
        gl16(Bg1 + ko, &BhS[cur ^ 1][lo1]);
      }
      bf16x8 ah[4], bh[4];
      #pragma unroll
      for (int i = 0; i < 4; i++) {
        ah[i] = *(const bf16x8*)&AhS[cur][swz(wm + i * 16 + l15, l4)];
        bh[i] = *(const bf16x8*)&BhS[cur][swz(wn + i * 16 + l15, l4)];
      }
      #pragma unroll
      for (int i = 0; i < 4; i++)
        #pragma unroll
        for (int j = 0; j < 4; j++)
          acc[i][j] = mfma16(ah[i], bh[j], acc[i][j]);
      asm volatile("s_waitcnt vmcnt(0)" ::: "memory");
      __syncthreads();
      cur ^= 1;
    }
  } else {
    // ===== fp32-A split path: A AND B register-prefetched (R5 structure) =====
    const int rr = tid >> 1, c2 = (tid & 1) << 1;
    const float* Arow = (const float*)Ap + (long long)(row0 + rr) * lda;
    const u16* Bhrow = Bhp + (long long)e * bstride + (long long)(col0 + rr) * Ksz;
    const u16* Blrow = Blp + (long long)e * bstride + (long long)(col0 + rr) * Ksz;
    uint4 sah0, sah1, sal0, sal1, sbh0, sbh1, sbl0, sbl1;
    auto gload = [&](int k0) {
      const float4* ap = (const float4*)(Arow + k0 + c2 * 8);
      float4 f0 = ap[0], f1 = ap[1], f2 = ap[2], f3 = ap[3];
      float h0 = bfhi_f(f0.x), h1 = bfhi_f(f0.y), h2 = bfhi_f(f0.z), h3 = bfhi_f(f0.w);
      float h4 = bfhi_f(f1.x), h5 = bfhi_f(f1.y), h6 = bfhi_f(f1.z), h7 = bfhi_f(f1.w);
      sah0 = make_uint4(rne2(h0, h1), rne2(h2, h3), rne2(h4, h5), rne2(h6, h7));
      sal0 = make_uint4(rne2(f0.x - h0, f0.y - h1), rne2(f0.z - h2, f0.w - h3),
                        rne2(f1.x - h4, f1.y - h5), rne2(f1.z - h6, f1.w - h7));
      h0 = bfhi_f(f2.x); h1 = bfhi_f(f2.y); h2 = bfhi_f(f2.z); h3 = bfhi_f(f2.w);
      h4 = bfhi_f(f3.x); h5 = bfhi_f(f3.y); h6 = bfhi_f(f3.z); h7 = bfhi_f(f3.w);
      sah1 = make_uint4(rne2(h0, h1), rne2(h2, h3), rne2(h4, h5), rne2(h6, h7));
      sal1 = make_uint4(rne2(f2.x - h0, f2.y - h1), rne2(f2.z - h2, f2.w - h3),
                        rne2(f3.x - h4, f3.y - h5), rne2(f3.z - h6, f3.w - h7));
      const uint4* bp = (const uint4*)(Bhrow + k0 + c2 * 8);
      sbh0 = bp[0]; sbh1 = bp[1];
      const uint4* blp2 = (const uint4*)(Blrow + k0 + c2 * 8);
      sbl0 = blp2[0]; sbl1 = blp2[1];
    };
    gload(0);
    for (int kt = 0; kt < nk; kt++) {
      __syncthreads();
      *(uint4*)&AhS[0][swz(rr, c2)]     = sah0;
      *(uint4*)&AhS[0][swz(rr, c2 + 1)] = sah1;
      *(uint4*)&AlS[swz(rr, c2)]        = sal0;
      *(uint4*)&AlS[swz(rr, c2 + 1)]    = sal1;
      *(uint4*)&BhS[0][swz(rr, c2)]     = sbh0;
      *(uint4*)&BhS[0][swz(rr, c2 + 1)] = sbh1;
      *(uint4*)&BlS[swz(rr, c2)]        = sbl0;
      *(uint4*)&BlS[swz(rr, c2 + 1)]    = sbl1;
      __syncthreads();
      if (kt + 1 < nk) gload((kt + 1) << 5);   // global loads hidden under MFMAs below

      bf16x8 ah[4], bh[4], al[4], bl[4];
      #pragma unroll
      for (int i = 0; i < 4; i++) {
        const int ar = wm + i * 16 + l15;
        const int br = wn + i * 16 + l15;
        ah[i] = *(const bf16x8*)&AhS[0][swz(ar, l4)];
        bh[i] = *(const bf16x8*)&BhS[0][swz(br, l4)];
        al[i] = *(const bf16x8*)&AlS[swz(ar, l4)];
        bl[i] = *(const bf16x8*)&BlS[swz(br, l4)];
      }
      #pragma unroll
      for (int i = 0; i < 4; i++) {
        #pragma unroll
        for (int j = 0; j < 4; j++) {
          acc[i][j] = mfma16(ah[i], bh[j], acc[i][j]);
          acc[i][j] = mfma16(ah[i], bl[j], acc[i][j]);
          acc[i][j] = mfma16(al[i], bh[j], acc[i][j]);
        }
      }
    }
  }

  #pragma unroll
  for (int i = 0; i < 4; i++) {
    #pragma unroll
    for (int j = 0; j < 4; j++) {
      const int orow0 = row0 + wm + i * 16 + (l4 << 2);
      const int ocol  = col0 + wn + j * 16 + l15;
      const float bv = biasp[(long long)e * bias_stride + col0 + wn + j * 16 + l15];
      #pragma unroll
      for (int q = 0; q < 4; q++) {
        float v = acc[i][j][q] + bv;
        if constexpr (DORELU) v = fmaxf(v, 0.f);
        const long long orow = orow0 + q;
        if constexpr (DOSCALE) v *= slot_wp[orow];
        if constexpr (OBF == 2) {
          const float vs = v * cscale;
          const float hi = bfhi_f(vs);
          ((u16*)Cp )[orow * ldc + ocol] = (u16)(__float_as_uint(hi) >> 16);
          ((u16*)Cp2)[orow * ldc + ocol] = rne1(vs - hi);
        } else if constexpr (OBF == 1) {
          ((u16*)Cp)[orow * ldc + ocol] = rne1(v);
        } else {
          ((float*)Cp)[orow * ldc + ocol] = v;
        }
      }
    }
  }
}

// ---------------- MFMA flash attention with stoichiometric bias ----------------
// grid (B*H=64, T/128=8), block 256 (4 waves); wave handles 32 q rows.
__global__ __launch_bounds__(256, 2)
void attn_mfma(const u16* __restrict__ Qh, const u16* __restrict__ Ql,
               const u16* __restrict__ Kh, const u16* __restrict__ Kl, int ldq,
               const u16* __restrict__ Vth, const u16* __restrict__ Vtl,
               const float* __restrict__ frac,
               const float* __restrict__ apos, const float* __restrict__ aneg,
               float* __restrict__ ctx)
{
  __shared__ __align__(16) u16 KhS[64 * 64];   // [kv][d], chunk^(kv&7) swizzle
  __shared__ __align__(16) u16 KlS[64 * 64];
  __shared__ __align__(16) u16 VhS[64 * 64];   // [d][kv], same swizzle
  __shared__ __align__(16) u16 VlS[64 * 64];
  __shared__ __align__(16) u16 PS[4][32][72];  // per-wave P[q][kv], +8 pad
  __shared__ __align__(16) float fjS[64];

  const int bh = blockIdx.x, b = bh >> 4, h = bh & 15;
  const int tid = threadIdx.x, wid = tid >> 6, lane = tid & 63;
  const int l15 = lane & 15, l4 = lane >> 4;
  const int q0 = blockIdx.y * 128 + wid * 32;

  bf16x8 qh[2][2], ql[2][2];
  #pragma unroll
  for (int ni = 0; ni < 2; ni++) {
    const long long qoff = (long long)(b * N_T + q0 + ni * 16 + l15) * ldq + h * 64 + l4 * 8;
    #pragma unroll
    for (int ks = 0; ks < 2; ks++) {
      qh[ni][ks] = *(const bf16x8*)(Qh + qoff + ks * 32);
      ql[ni][ks] = *(const bf16x8*)(Ql + qoff + ks * 32);
    }
  }
  float fq[2];
  #pragma unroll
  for (int ni = 0; ni < 2; ni++) fq[ni] = frac[b * N_T + q0 + ni * 16 + l15];
  const float ap = apos[h], an = aneg[h];

  f32x4 acc[4][2] = {};                 // O^T: d = md*16+l4*4+reg, q = nq*16+l15
  float mrun[2] = {-3.0e38f, -3.0e38f}, lrun[2] = {0.f, 0.f};

  const int sr = tid >> 2, scb = (tid & 3) << 4;
  const int ch0 = ((scb >> 3) ^ (sr & 7)) << 3;
  const int ch1 = (((scb >> 3) + 1) ^ (sr & 7)) << 3;

  for (int kt = 0; kt < 16; kt++) {
    __syncthreads();
    {
      const long long koff = (long long)(b * N_T + kt * 64 + sr) * ldq + h * 64 + scb;
      const uint4* khp = (const uint4*)(Kh + koff);
      const uint4* klp = (const uint4*)(Kl + koff);
      const long long voff = (long long)(bh * 64 + sr) * N_T + kt * 64 + scb;
      const uint4* vhp = (const uint4*)(Vth + voff);
      const uint4* vlp = (const uint4*)(Vtl + voff);
      *(uint4*)&KhS[sr * 64 + ch0] = khp[0];
      *(uint4*)&KhS[sr * 64 + ch1] = khp[1];
      *(uint4*)&KlS[sr * 64 + ch0] = klp[0];
      *(uint4*)&KlS[sr * 64 + ch1] = klp[1];
      *(uint4*)&VhS[sr * 64 + ch0] = vhp[0];
      *(uint4*)&VhS[sr * 64 + ch1] = vhp[1];
      *(uint4*)&VlS[sr * 64 + ch0] = vlp[0];
      *(uint4*)&VlS[sr * 64 + ch1] = vlp[1];
    }
    if (tid < 64) fjS[tid] = frac[b * N_T + kt * 64 + tid];
    __syncthreads();

    // ---- S^T = K * Q^T (3-term split)
    f32x4 s[4][2] = {};
    #pragma unroll
    for (int ks = 0; ks < 2; ks++) {
      bf16x8 kh[4], kl[4];
      #pragma unroll
      for (int mj = 0; mj < 4; mj++) {
        const int row = mj * 16 + l15;
        const int ch = (((ks << 2) + l4) ^ (row & 7)) << 3;
        kh[mj] = *(const bf16x8*)&KhS[row * 64 + ch];
        kl[mj] = *(const bf16x8*)&KlS[row * 64 + ch];
      }
      #pragma unroll
      for (int mj = 0; mj < 4; mj++) {
        #pragma unroll
        for (int ni = 0; ni < 2; ni++) {
          s[mj][ni] = mfma16(kh[mj], qh[ni][ks], s[mj][ni]);
          s[mj][ni] = mfma16(kh[mj], ql[ni][ks], s[mj][ni]);
          s[mj][ni] = mfma16(kl[mj], qh[ni][ks], s[mj][ni]);
        }
      }
    }

    // ---- bias (scalar fjS reads) ; kv = mj*16 + l4*4 + r, q = ni*16 + l15
    #pragma unroll
    for (int mj = 0; mj < 4; mj++) {
      const int kvb = mj * 16 + l4 * 4;
      const float f0 = fjS[kvb], f1 = fjS[kvb + 1], f2 = fjS[kvb + 2], f3 = fjS[kvb + 3];
      #pragma unroll
      for (int ni = 0; ni < 2; ni++) {
        float d0 = f0 - fq[ni], d1 = f1 - fq[ni], d2 = f2 - fq[ni], d3 = f3 - fq[ni];
        s[mj][ni][0] += (d0 > 0.f ? ap : an) * d0;
        s[mj][ni][1] += (d1 > 0.f ? ap : an) * d1;
        s[mj][ni][2] += (d2 > 0.f ? ap : an) * d2;
        s[mj][ni][3] += (d3 > 0.f ? ap : an) * d3;
      }
    }

    // ---- online softmax
    #pragma unroll
    for (int ni = 0; ni < 2; ni++) {
      float tm = s[0][ni][0];
      #pragma unroll
      for (int mj = 0; mj < 4; mj++) {
        tm = fmaxf(tm, fmaxf(fmaxf(s[mj][ni][0], s[mj][ni][1]),
                             fmaxf(s[mj][ni][2], s[mj][ni][3])));
      }
      tm = fmaxf(tm, __shfl_xor(tm, 16, 64));
      tm = fmaxf(tm, __shfl_xor(tm, 32, 64));
      const float nm = fmaxf(mrun[ni], tm);
      const float cor = __expf(mrun[ni] - nm);
      mrun[ni] = nm;
      lrun[ni] *= cor;
      #pragma unroll
      for (int md = 0; md < 4; md++) {
        acc[md][ni][0] *= cor; acc[md][ni][1] *= cor;
        acc[md][ni][2] *= cor; acc[md][ni][3] *= cor;
      }
      float rsum = 0.f;
      #pragma unroll
      for (int mj = 0; mj < 4; mj++) {
        #pragma unroll
        for (int r = 0; r < 4; r++) {
          const float p = __expf(s[mj][ni][r] - nm);
          s[mj][ni][r] = p;
          rsum += p;
        }
      }
      rsum += __shfl_xor(rsum, 16, 64);
      rsum += __shfl_xor(rsum, 32, 64);
      lrun[ni] += rsum;
    }

    // ---- P hi -> per-wave LDS (C-write-verified mapping), read B-frags
    #pragma unroll
    for (int ni = 0; ni < 2; ni++) {
      #pragma unroll
      for (int mj = 0; mj < 4; mj++) {
        float h0 = bfhi_f(s[mj][ni][0]), h1 = bfhi_f(s[mj][ni][1]);
        float h2 = bfhi_f(s[mj][ni][2]), h3 = bfhi_f(s[mj][ni][3]);
        u32* dst = (u32*)&PS[wid][ni * 16 + l15][mj * 16 + l4 * 4];
        dst[0] = rne2(h0, h1); dst[1] = rne2(h2, h3);
      }
    }
    bf16x8 pbh[2][2];
    #pragma unroll
    for (int ni = 0; ni < 2; ni++)
      #pragma unroll
      for (int ks = 0; ks < 2; ks++)
        pbh[ni][ks] = *(const bf16x8*)&PS[wid][ni * 16 + l15][ks * 32 + l4 * 8];

    // ---- P lo -> same LDS buffer, read B-frags
    #pragma unroll
    for (int ni = 0; ni < 2; ni++) {
      #pragma unroll
      for (int mj = 0; mj < 4; mj++) {
        float p0 = s[mj][ni][0], p1 = s[mj][ni][1], p2 = s[mj][ni][2], p3 = s[mj][ni][3];
        float h0 = bfhi_f(p0), h1 = bfhi_f(p1), h2 = bfhi_f(p2), h3 = bfhi_f(p3);
        u32* dst = (u32*)&PS[wid][ni * 16 + l15][mj * 16 + l4 * 4];
        dst[0] = rne2(p0 - h0, p1 - h1); dst[1] = rne2(p2 - h2, p3 - h3);
      }
    }
    bf16x8 pbl[2][2];
    #pragma unroll
    for (int ni = 0; ni < 2; ni++)
      #pragma unroll
      for (int ks = 0; ks < 2; ks++)
        pbl[ni][ks] = *(const bf16x8*)&PS[wid][ni * 16 + l15][ks * 32 + l4 * 8];

    // ---- O^T += V^T * P^T (3-term split; linear kv pairing)
    #pragma unroll
    for (int md = 0; md < 4; md++) {
      #pragma unroll
      for (int ks = 0; ks < 2; ks++) {
        const int row = md * 16 + l15;
        const int ch = (((ks << 2) + l4) ^ (row & 7)) << 3;
        const bf16x8 vh = *(const bf16x8*)&VhS[row * 64 + ch];
        const bf16x8 vl = *(const bf16x8*)&VlS[row * 64 + ch];
        #pragma unroll
        for (int nq = 0; nq < 2; nq++) {
          acc[md][nq] = mfma16(vh, pbh[nq][ks], acc[md][nq]);
          acc[md][nq] = mfma16(vh, pbl[nq][ks], acc[md][nq]);
          acc[md][nq] = mfma16(vl, pbh[nq][ks], acc[md][nq]);
        }
      }
    }
  }

  // ---- epilogue: ctx[q][d] = O^T[d][q] / l[q]
  const float inv[2] = {1.f / lrun[0], 1.f / lrun[1]};
  #pragma unroll
  for (int nq = 0; nq < 2; nq++) {
    #pragma unroll
    for (int md = 0; md < 4; md++) {
      float4 o;
      o.x = acc[md][nq][0] * inv[nq];
      o.y = acc[md][nq][1] * inv[nq];
      o.z = acc[md][nq][2] * inv[nq];
      o.w = acc[md][nq][3] * inv[nq];
      *(float4*)(ctx + (long long)(b * N_T + q0 + nq * 16 + l15) * N_D +
                 h * 64 + md * 16 + l4 * 4) = o;
    }
  }
}

// ---------------- LN1 + gate softmax + top2 (wave per token; NO device atomics) -------------
__global__ __launch_bounds__(256, 4)
void ln1_gate(const float* __restrict__ src, const float* __restrict__ attnout,
              const float* __restrict__ g, const float* __restrict__ bb,
              const float* __restrict__ gateW, const float* __restrict__ gateb,
              float* __restrict__ xout, u16* __restrict__ xbf,
              int2* __restrict__ tok_top, float2* __restrict__ tok_w)
{
  const int wid = threadIdx.x >> 6, lane = threadIdx.x & 63;
  const int t = blockIdx.x * 4 + wid;
  const float4* s4 = (const float4*)(src + (long long)t * N_D);
  const float4* a4 = (const float4*)(attnout + (long long)t * N_D);
  float4 v[4];
  float sum = 0.f;
  #pragma unroll
  for (int c = 0; c < 4; c++) {
    const int idx = c * 64 + lane;
    float4 a = s4[idx], b2 = a4[idx];
    v[c] = make_float4(a.x + b2.x, a.y + b2.y, a.z + b2.z, a.w + b2.w);
    sum += v[c].x + v[c].y + v[c].z + v[c].w;
  }
  sum = wred(sum);
  const float mu = sum * (1.f / 1024.f);
  float s2 = 0.f;
  #pragma unroll
  for (int c = 0; c < 4; c++) {
    float dx = v[c].x - mu, dy = v[c].y - mu, dz = v[c].z - mu, dw = v[c].w - mu;
    s2 += dx * dx + dy * dy + dz * dz + dw * dw;
  }
  s2 = wred(s2);
  const float rs = rsqrtf(s2 * (1.f / 1024.f) + LNEPS);
  float acc[8];
  #pragma unroll
  for (int e2 = 0; e2 < 8; e2++) acc[e2] = 0.f;
  #pragma unroll
  for (int c = 0; c < 4; c++) {
    const int idx = c * 64 + lane;
    float4 gv = ((const float4*)g)[idx], bv = ((const float4*)bb)[idx];
    float xa[4];
    xa[0] = (v[c].x - mu) * rs * gv.x + bv.x;
    xa[1] = (v[c].y - mu) * rs * gv.y + bv.y;
    xa[2] = (v[c].z - mu) * rs * gv.z + bv.z;
    xa[3] = (v[c].w - mu) * rs * gv.w + bv.w;
    ((float4*)(xout + (long long)t * N_D))[idx] = make_float4(xa[0], xa[1], xa[2], xa[3]);
    *(uint2*)&xbf[(long long)t * N_D + idx * 4] =
        make_uint2(rne2(xa[0], xa[1]), rne2(xa[2], xa[3]));
    #pragma unroll
    for (int ii = 0; ii < 4; ii++) {
      const float xs = xa[ii];
      const float4* gw = (const float4*)(gateW + ((long long)(idx * 4 + ii)) * N_E);
      float4 w0 = gw[0], w1 = gw[1];
      acc[0] += xs * w0.x; acc[1] += xs * w0.y; acc[2] += xs * w0.z; acc[3] += xs * w0.w;
      acc[4] += xs * w1.x; acc[5] += xs * w1.y; acc[6] += xs * w1.z; acc[7] += xs * w1.w;
    }
  }
  #pragma unroll
  for (int e2 = 0; e2 < 8; e2++) acc[e2] = wred(acc[e2]);
  if (lane == 0) {
    float lg[8];
    #pragma unroll
    for (int e2 = 0; e2 < 8; e2++) lg[e2] = acc[e2] + gateb[e2];
    float mx = lg[0];
    #pragma unroll
    for (int e2 = 1; e2 < 8; e2++) mx = fmaxf(mx, lg[e2]);
    float Z = 0.f;
    #pragma unroll
    for (int e2 = 0; e2 < 8; e2++) Z += __expf(lg[e2] - mx);
    int e0 = 0; float v0 = lg[0];
    #pragma unroll
    for (int e2 = 1; e2 < 8; e2++) if (lg[e2] > v0) { v0 = lg[e2]; e0 = e2; }
    int e1 = -1; float v1 = -3.4e38f;
    #pragma unroll
    for (int e2 = 0; e2 < 8; e2++) if (e2 != e0 && lg[e2] > v1) { v1 = lg[e2]; e1 = e2; }
    tok_top[t] = make_int2(e0, e1);
    tok_w[t] = make_float2(__expf(v0 - mx) / Z, __expf(v1 - mx) / Z);
  }
}

// ---------------- routing: histogram tok_top, offsets, tiles, padding fill ----------------
__global__ __launch_bounds__(256)
void route_build(const int2* __restrict__ tok_top, int* __restrict__ offsets,
                 int* __restrict__ cursors, int* __restrict__ ntiles,
                 int2* __restrict__ tiles, int* __restrict__ token_idx,
                 float* __restrict__ slot_w)
{
  __shared__ int cnt[N_E];
  __shared__ int soff[N_E + 1];
  __shared__ int scnt[N_E];
  const int tid = threadIdx.x;
  if (tid < N_E) cnt[tid] = 0;
  __syncthreads();
  int lc0 = 0, lc1 = 0, lc2 = 0, lc3 = 0, lc4 = 0, lc5 = 0, lc6 = 0, lc7 = 0;
  for (int t = tid; t < N_BT; t += 256) {
    const int2 ee = tok_top[t];
    lc0 += (ee.x == 0) + (ee.y == 0); lc1 += (ee.x == 1) + (ee.y == 1);
    lc2 += (ee.x == 2) + (ee.y == 2); lc3 += (ee.x == 3) + (ee.y == 3);
    lc4 += (ee.x == 4) + (ee.y == 4); lc5 += (ee.x == 5) + (ee.y == 5);
    lc6 += (ee.x == 6) + (ee.y == 6); lc7 += (ee.x == 7) + (ee.y == 7);
  }
  if (lc0) atomicAdd(&cnt[0], lc0); if (lc1) atomicAdd(&cnt[1], lc1);
  if (lc2) atomicAdd(&cnt[2], lc2); if (lc3) atomicAdd(&cnt[3], lc3);
  if (lc4) atomicAdd(&cnt[4], lc4); if (lc5) atomicAdd(&cnt[5], lc5);
  if (lc6) atomicAdd(&cnt[6], lc6); if (lc7) atomicAdd(&cnt[7], lc7);
  __syncthreads();
  if (tid == 0) {
    int off = 0, nt = 0;
    for (int ex = 0; ex < N_E; ex++) {
      soff[ex] = off; offsets[ex] = off; cursors[ex] = 0;
      const int c = cnt[ex];
      scnt[ex] = c;
      const int pt = (c + 127) >> 7;
      for (int i = 0; i < pt; i++) { tiles[nt] = make_int2(ex, off + i * 128); nt++; }
      off += pt << 7;
    }
    soff[N_E] = off; offsets[N_E] = off;
    *ntiles = nt;
  }
  __syncthreads();
  for (int ex = 0; ex < N_E; ex++)
    for (int s = soff[ex] + scnt[ex] + tid; s < soff[ex + 1]; s += 256) {
      token_idx[s] = 0; slot_w[s] = 0.f;
    }
}

__global__ __launch_bounds__(256)
void route_scatter(const int2* __restrict__ tok_top, const float2* __restrict__ tok_w,
                   const int* __restrict__ offsets, int* __restrict__ cursors,
                   int* __restrict__ token_idx, float* __restrict__ slot_w,
                   int* __restrict__ slotA, int* __restrict__ slotB)
{
  const int t = blockIdx.x * 256 + threadIdx.x;
  if (t >= N_BT) return;
  const int2 ee = tok_top[t];
  const float2 ww = tok_w[t];
  int p = atomicAdd(&cursors[ee.x], 1);
  int s = offsets[ee.x] + p;
  token_idx[s] = t; slot_w[s] = ww.x; slotA[t] = s;
  p = atomicAdd(&cursors[ee.y], 1);
  s = offsets[ee.y] + p;
  token_idx[s] = t; slot_w[s] = ww.y; slotB[t] = s;
}

// ---------------- final: y = LN2(x + out2[sA] + out2[sB])  (out2 is bf16) ----------------
__global__ __launch_bounds__(256, 4)
void final_ln2(const float* __restrict__ x, const u16* __restrict__ out2,
               const int* __restrict__ slotA, const int* __restrict__ slotB,
               const float* __restrict__ g, const float* __restrict__ bb,
               float* __restrict__ out)
{
  const int wid = threadIdx.x >> 6, lane = threadIdx.x & 63;
  const int t = blockIdx.x * 4 + wid;
  const int sA = slotA[t], sB = slotB[t];
  const float4* xr = (const float4*)(x + (long long)t * N_D);
  const u16* pa = out2 + (long long)sA * N_D;
  const u16* pb = out2 + (long long)sB * N_D;
  float4 v[4];
  float sum = 0.f;
  #pragma unroll
  for (int c = 0; c < 4; c++) {
    const int idx = c * 64 + lane;
    float4 a = xr[idx];
    uint2 ua = *(const uint2*)&pa[idx * 4];
    uint2 ub = *(const uint2*)&pb[idx * 4];
    float a0 = __uint_as_float(ua.x << 16), a1 = __uint_as_float(ua.x & 0xffff0000u);
    float a2 = __uint_as_float(ua.y << 16), a3 = __uint_as_float(ua.y & 0xffff0000u);
    float b0 = __uint_as_float(ub.x << 16), b1 = __uint_as_float(ub.x & 0xffff0000u);
    float b2 = __uint_as_float(ub.y << 16), b3 = __uint_as_float(ub.y & 0xffff0000u);
    v[c] = make_float4(a.x + a0 + b0, a.y + a1 + b1, a.z + a2 + b2, a.w + a3 + b3);
    sum += v[c].x + v[c].y + v[c].z + v[c].w;
  }
  sum = wred(sum);
  const float mu = sum * (1.f / 1024.f);
  float s2 = 0.f;
  #pragma unroll
  for (int c = 0; c < 4; c++) {
    float dx = v[c].x - mu, dy = v[c].y - mu, dz = v[c].z - mu, dw = v[c].w - mu;
    s2 += dx * dx + dy * dy + dz * dz + dw * dw;
  }
  s2 = wred(s2);
  const float rs = rsqrtf(s2 * (1.f / 1024.f) + LNEPS);
  #pragma unroll
  for (int c = 0; c < 4; c++) {
    const int idx = c * 64 + lane;
    float4 gv = ((const float4*)g)[idx], bv = ((const float4*)bb)[idx];
    float4 o;
    o.x = (v[c].x - mu) * rs * gv.x + bv.x;
    o.y = (v[c].y - mu) * rs * gv.y + bv.y;
    o.z = (v[c].z - mu) * rs * gv.z + bv.z;
    o.w = (v[c].w - mu) * rs * gv.w + bv.w;
    ((float4*)(out + (long long)t * N_D))[idx] = o;
  }
}

// ---------------- launch ----------------
extern "C" void kernel_launch(void* const* d_in, const int* in_sizes, int n_in,
                              void* d_out, int out_size, void* d_ws, size_t ws_size,
                              hipStream_t stream)
{
  const float* src   = (const float*)d_in[0];
  const float* frac  = (const float*)d_in[1];
  const float* Wq    = (const float*)d_in[2];
  const float* bq    = (const float*)d_in[3];
  const float* Wk    = (const float*)d_in[4];
  const float* bk    = (const float*)d_in[5];
  const float* Wv    = (const float*)d_in[6];
  const float* bv    = (const float*)d_in[7];
  const float* Wo    = (const float*)d_in[8];
  const float* bo    = (const float*)d_in[9];
  const float* apos  = (const float*)d_in[10];
  const float* aneg  = (const float*)d_in[11];
  const float* gateW = (const float*)d_in[12];
  const float* gateb = (const float*)d_in[13];
  const float* W1    = (const float*)d_in[14];
  const float* b1    = (const float*)d_in[15];
  const float* W2    = (const float*)d_in[16];
  const float* b2    = (const float*)d_in[17];
  const float* ln1g  = (const float*)d_in[18];
  const float* ln1b  = (const float*)d_in[19];
  const float* ln2g  = (const float*)d_in[20];
  const float* ln2b  = (const float*)d_in[21];
  float* out = (float*)d_out;

  char* ws = (char*)d_ws;
  const size_t MB = 1ull << 20;
  u16* Bcath = (u16*)(ws + 0 * MB);
  u16* Bcatl = (u16*)(ws + 6 * MB);
  u16* WoTh  = (u16*)(ws + 12 * MB);
  u16* WoTl  = (u16*)(ws + 14 * MB);
  u16*   W1T  = (u16*)(ws + 16 * MB);    // 64 MB, dead after FFN GEMM1
  u16*   out2 = (u16*)(ws + 16 * MB);    // <=19 MB bf16, alias (written after W1T dead)
  u16*   W2T  = (u16*)(ws + 80 * MB);    // 64 MB
  u16*   QKVh = (u16*)(ws + 144 * MB);   // 24 MB: [4096][3072] hi (Q|K|V)
  u16*   QKVl = (u16*)(ws + 168 * MB);   // 24 MB lo
  u16*   Vth  = (u16*)(ws + 192 * MB);   // 8 MB per-head V^T hi
  u16*   Vtl  = (u16*)(ws + 200 * MB);   // 8 MB per-head V^T lo
  float* ctxb = (float*)(ws + 208 * MB); // 16 MB
  float* attnb= (float*)(ws + 144 * MB); // 16 MB alias (QKVh dead after attn)
  u16*   hb   = (u16*)(ws + 144 * MB);   // <=72 MB alias (all of 144-216 dead by FFN1)
  float* xb   = (float*)(ws + 224 * MB); // 16 MB fp32 -> total 240 MB
  u16*   xbf  = (u16*)(ws + 4 * MB);     // 8 MB bf16 alias (Bcat dead by ln1_gate)
  float* bcat = (float*)(ws + 240 * MB); // 12 KB
  char* misc = ws + 0;                   // aliases Bcat region (dead by routing phase)
  int*    cursors   = (int*)(misc + 64);
  int*    offsets   = (int*)(misc + 128);
  int*    ntiles    = (int*)(misc + 256);
  int2*   tiles     = (int2*)(misc + 512);
  int2*   tok_top   = (int2*)(misc + 2048);
  float2* tok_w     = (float2*)(misc + 2048 + 32768);
  int*    token_idx = (int*)(misc + 2048 + 65536);
  float*  slot_w    = (float*)(misc + 2048 + 65536 + 36864);
  int*    slotA     = (int*)(misc + 2048 + 65536 + 73728);
  int*    slotB     = (int*)(misc + 2048 + 65536 + 73728 + 16384);

  dim3 b256(256);
  trans4<<<dim3(16, 16, 4), b256, 0, stream>>>(Wq, Wk, Wv, Wo, Bcath, Bcatl, WoTh, WoTl);
  transpose_bf16<0><<<dim3(64, 16, 8), b256, 0, stream>>>(W1, W1T, nullptr, 1024, 4096, 1.0f);
  transpose_bf16<0><<<dim3(16, 64, 8), b256, 0, stream>>>(W2, W2T, nullptr, 4096, 1024, 1.0f);
  bias_cat<<<dim3(12), b256, 0, stream>>>(bq, bk, bv, bcat);

  // fused QKV projection: [4096][3072] hi/lo bf16 (Q cols pre-scaled via Wq/bq); CG=3
  gemm128<1, 0, 0, 0, 2, 0, 3><<<dim3(32, 24), b256, 0, stream>>>(
      src, 1024, Bcath, Bcatl, 0, QKVh, 3072, bcat, 0, nullptr, nullptr, nullptr, nullptr,
      1024, QKVl, 1.0f);

  vtrans_bf16<<<dim3(16, 64), b256, 0, stream>>>(QKVh + 2048, QKVl + 2048, 3072, Vth, Vtl);

  attn_mfma<<<dim3(64, 8), b256, 0, stream>>>(QKVh, QKVl, QKVh + 1024, QKVl + 1024, 3072,
                                              Vth, Vtl, frac, apos, aneg, ctxb);

  gemm128<1, 0, 0, 0, 0, 0, 1><<<dim3(32, 8), b256, 0, stream>>>(
      ctxb, 1024, WoTh, WoTl, 0, attnb, 1024, bo, 0, nullptr, nullptr, nullptr, nullptr,
      1024, nullptr, 1.0f);

  ln1_gate<<<dim3(1024), b256, 0, stream>>>(src, attnb, ln1g, ln1b, gateW, gateb,
                                            xb, xbf, tok_top, tok_w);
  route_build<<<dim3(1), b256, 0, stream>>>(tok_top, offsets, cursors, ntiles,
                                            tiles, token_idx, slot_w);
  route_scatter<<<dim3(16), b256, 0, stream>>>(tok_top, tok_w, offsets, cursors,
                                               token_idx, slot_w, slotA, slotB);

  // grouped MoE FFN (bf16 A+B, R8 double-buffered global_load_lds staging)
  gemm128<0, 1, 1, 0, 1, 1, 4><<<dim3(72, 32), b256, 0, stream>>>(
      xbf, 1024, W1T, nullptr, 4096ll * 1024, hb, 4096, b1, 4096,
      nullptr, token_idx, tiles, ntiles, 1024, nullptr, 1.0f);
  gemm128<0, 0, 0, 1, 1, 1, 8><<<dim3(72, 8), b256, 0, stream>>>(
      hb, 4096, W2T, nullptr, 1024ll * 4096, out2, 1024, b2, 1024,
      slot_w, nullptr, tiles, ntiles, 4096, nullptr, 1.0f);

  final_ln2<<<dim3(1024), b256, 0, stream>>>(xb, out2, slotA, slotB, ln2g, ln2b, out);
}